// Round 3
// baseline (324.218 us; speedup 1.0000x reference)
//
#include <hip/hip_runtime.h>

// ROIPooler (FPN multi-level ROIAlign, aligned=true), float32 in/out.
// R8: NC=16 / tight CAPU / single barrier / hoisted staging math.
//  - Window bound analysis: span <= (6.5/7)*box*scale; per-level size coupling
//    caps L4 at ~50 16B-units -> CAPU=76 (52% margin; fallback kept for safety).
//  - NC=16 channels/block, LDS 19.9KB -> 8 blocks/CU (32 waves, 100%).
//    Grid 512 x 16 = 8192 blocks (4x fewer): prologue/barrier/drain amortized.
//  - All threads derive window bounds from samples 0 & 13 (monotone) -> staging
//    needs no setup barrier; ONE __syncthreads covers DMA drain + table writes.
//  - Staging: (y,x4) decomposition per 64-lane tile hoisted out of the channel
//    loop (channel-independent); per-DMA work = shift/add + clamp + DMA.
//  - Sample tables packed int2/float2, ry pre-multiplied by row stride ->
//    4x ds_read_b64 per output instead of 16x b32 param reads.

#define OUTD 7
#define SD   14      // OUT*SR samples per axis
#define CCH  256
#define NBOX 256
#define NC   16      // channels per block
#define NCHK (CCH / NC)   // 16 chunks
#define CAPU 76      // 16B units per channel slot (analytic max ~50)
#define CAPF (CAPU * 4)   // 304 floats
#define NBIN (OUTD * OUTD)
#define NOUT (NC * NBIN)  // 784

typedef __attribute__((address_space(1))) unsigned int gu32;
typedef __attribute__((address_space(3))) unsigned int lu32;

__device__ __forceinline__ void gl2lds16(const float* g, float* l) {
    // 16B per lane: LDS dst = uniform base + lane*16, global src per-lane.
    __builtin_amdgcn_global_load_lds((gu32*)(unsigned long long)g, (lu32*)l, 16, 0, 0);
}

__global__ __launch_bounds__(256) void roi_direct(
    const float* __restrict__ f0, const float* __restrict__ f1,
    const float* __restrict__ f2, const float* __restrict__ f3,
    const float* __restrict__ boxes, float* __restrict__ out)
{
    const int roi = blockIdx.x;
    const int c0  = blockIdx.y * NC;
    const int t   = threadIdx.x;
    const int b   = roi >> 8;            // roi / NBOX

    const float bx1 = boxes[roi * 4 + 0];
    const float by1 = boxes[roi * 4 + 1];
    const float bx2 = boxes[roi * 4 + 2];
    const float by2 = boxes[roi * 4 + 3];

    // Level assignment (block-uniform).
    const float area = (bx2 - bx1) * (by2 - by1);
    const float sz   = sqrtf(area);
    int lvl = (int)floorf(4.0f + log2f(sz * (1.0f / 224.0f) + 1e-8f));
    lvl = min(max(lvl, 2), 5) - 2;

    const int   wsh   = 8 - lvl;          // log2(W), W = H
    const int   H     = 1 << wsh;
    const int   W     = H;
    const float scale = 1.0f / (float)(4 << lvl);
    const size_t HW   = (size_t)1 << (2 * wsh);

    const float* f  = (lvl == 0) ? f0 : (lvl == 1) ? f1 : (lvl == 2) ? f2 : f3;
    const float* fb = f + (size_t)b * CCH * HW;

    __shared__ int2   s_py[SD], s_px[SD];
    __shared__ float2 s_wy[SD], s_wx[SD];
    __shared__ __align__(16) float s_win[NC * CAPF];   // 19456 B

    // ---- per-thread box geometry (uniform values, no LDS needed) ----
    const float x1r = bx1 * scale - 0.5f;
    const float y1r = by1 * scale - 0.5f;
    const float bw  = (bx2 - bx1) * scale * (1.0f / OUTD);
    const float bh  = (by2 - by1) * scale * (1.0f / OUTD);
    const float Wm1 = (float)(W - 1);

    // Window bounds from first/last samples (monotone: bw,bh >= 0).
    const float xs0  = x1r + 0.25f * bw, xs13 = x1r + 6.75f * bw;
    const float ys0  = y1r + 0.25f * bh, ys13 = y1r + 6.75f * bh;
    const int xf = (int)fminf(fmaxf(xs0, 0.0f), Wm1);
    const int yf = (int)fminf(fmaxf(ys0, 0.0f), Wm1);
    const int xl = min((int)fminf(fmaxf(xs13, 0.0f), Wm1) + 1, W - 1);
    const int yl = min((int)fminf(fmaxf(ys13, 0.0f), Wm1) + 1, W - 1);
    const int x_lo = xf & ~3;            // 16B-align left edge in source
    const int y_lo = yf;
    const int W4 = (xl - x_lo + 4) >> 2; // padded row width, 16B units
    const int Hw = yl - y_lo + 1;
    const int L4 = Hw * W4;              // window size, 16B units
    const int rs = W4 << 2;              // LDS row stride, floats

    // ---- sample tables (packed; pre-multiplied ry) ----
    if (t < SD) {
        const int i = t;
        const float g  = ((float)i + 0.5f) * 0.5f;
        const float ys = y1r + g * bh;
        const float xs = x1r + g * bw;
        const float vy = ((ys >= -1.0f) && (ys <= (float)H)) ? 1.0f : 0.0f;
        const float vx = ((xs >= -1.0f) && (xs <= (float)W)) ? 1.0f : 0.0f;
        const float yc = fminf(fmaxf(ys, 0.0f), Wm1);
        const float xc = fminf(fmaxf(xs, 0.0f), Wm1);
        const int y0 = (int)yc;
        const int x0 = (int)xc;
        const float ly = yc - (float)y0;
        const float lx = xc - (float)x0;
        s_py[i] = make_int2((y0 - y_lo) * rs, (min(y0 + 1, H - 1) - y_lo) * rs);
        s_px[i] = make_int2(x0 - x_lo, min(x0 + 1, W - 1) - x_lo);
        s_wy[i] = make_float2(vy * (1.0f - ly), vy * ly);
        s_wx[i] = make_float2(vx * (1.0f - lx), vx * lx);
    }

    float* ob = out + (size_t)roi * (CCH * NBIN) + (size_t)c0 * NBIN;

    if (L4 <= CAPU) {
        // -------- fast path (all realizable windows) --------
        const int wv = t >> 6, ln = t & 63;
        const int nT2 = (L4 > 64) ? 1 : 0;
        const float invW4 = 1.0f / (float)W4;

        // Channel-independent lane offsets for the (<=2) 64-unit tiles.
        int yA = (int)((float)ln * invW4);
        int xA = ln - yA * W4;
        if (xA < 0) { xA += W4; --yA; } else if (xA >= W4) { xA -= W4; ++yA; }
        const int offA = (yA << wsh) + (xA << 2);
        int yB = (int)((float)(ln + 64) * invW4);
        int xB = (ln + 64) - yB * W4;
        if (xB < 0) { xB += W4; --yB; } else if (xB >= W4) { xB -= W4; ++yB; }
        const int offB = (yB << wsh) + (xB << 2);

        const unsigned int wbase = ((unsigned int)y_lo << wsh) + (unsigned int)x_lo;
        const unsigned int cb0   = ((unsigned int)(b * CCH + c0) << (2 * wsh)) + wbase;
        const unsigned int gmax  = (512u << (2 * wsh)) - 4u;   // tensor floats - 4
        const int nIt = NC << nT2;
        for (int it = wv; it < nIt; it += 4) {
            const int c  = it >> nT2;
            const int tl = it & nT2;
            const int off = tl ? offB : offA;
            if (ln + (tl << 6) < L4) {
                unsigned int g = cb0 + ((unsigned int)c << (2 * wsh)) + (unsigned int)off;
                g = min(g, gmax);                   // tensor-end clamp (pad cols)
                gl2lds16(f + g, s_win + c * CAPF + (tl << 8));
            }
        }
        __syncthreads();   // one barrier: drains DMA + publishes tables

        for (int idx = t; idx < NOUT; idx += 256) {
            const int ci  = idx / NBIN;
            const int bin = idx - ci * NBIN;
            const int oy  = bin / 7;
            const int ox  = bin - oy * 7;
            const int ia = 2 * oy, ib = ia + 1;
            const int ja = 2 * ox, jb = ja + 1;
            const int2   pyA = s_py[ia], pyB = s_py[ib];
            const int2   pxA = s_px[ja], pxB = s_px[jb];
            const float2 wyA = s_wy[ia], wyB = s_wy[ib];
            const float2 wxA = s_wx[ja], wxB = s_wx[jb];
            const float* w = s_win + ci * CAPF;
            const float acc =
                wyA.x * (wxA.x * w[pyA.x + pxA.x] + wxA.y * w[pyA.x + pxA.y])
              + wyA.y * (wxA.x * w[pyA.y + pxA.x] + wxA.y * w[pyA.y + pxA.y])
              + wyA.x * (wxB.x * w[pyA.x + pxB.x] + wxB.y * w[pyA.x + pxB.y])
              + wyA.y * (wxB.x * w[pyA.y + pxB.x] + wxB.y * w[pyA.y + pxB.y])
              + wyB.x * (wxA.x * w[pyB.x + pxA.x] + wxA.y * w[pyB.x + pxA.y])
              + wyB.y * (wxA.x * w[pyB.y + pxA.x] + wxA.y * w[pyB.y + pxA.y])
              + wyB.x * (wxB.x * w[pyB.x + pxB.x] + wxB.y * w[pyB.x + pxB.y])
              + wyB.y * (wxB.x * w[pyB.y + pxB.x] + wxB.y * w[pyB.y + pxB.y]);
            ob[idx] = acc * 0.25f;   // coalesced 784-float store
        }
    } else {
        // -------- safety fallback: direct global gather (analytically dead) --
        for (int idx = t; idx < NOUT; idx += 256) {
            const int ci  = idx / NBIN;
            const int bin = idx - ci * NBIN;
            const int oy  = bin / 7;
            const int ox  = bin - oy * 7;
            const float* fc = fb + (size_t)(c0 + ci) * HW;
            float acc = 0.0f;
            #pragma unroll
            for (int sy = 0; sy < 2; ++sy) {
                const float gy = ((float)(2 * oy + sy) + 0.5f) * 0.5f;
                const float ys = y1r + gy * bh;
                const float vy = ((ys >= -1.0f) && (ys <= (float)H)) ? 1.0f : 0.0f;
                const float yc = fminf(fmaxf(ys, 0.0f), Wm1);
                const int   yy0 = (int)yc;
                const int   yy1 = min(yy0 + 1, H - 1);
                const float ly = yc - (float)yy0;
                #pragma unroll
                for (int sx = 0; sx < 2; ++sx) {
                    const float gx = ((float)(2 * ox + sx) + 0.5f) * 0.5f;
                    const float xs = x1r + gx * bw;
                    const float vx = ((xs >= -1.0f) && (xs <= (float)W)) ? 1.0f : 0.0f;
                    const float xc = fminf(fmaxf(xs, 0.0f), Wm1);
                    const int   xx0 = (int)xc;
                    const int   xx1 = min(xx0 + 1, W - 1);
                    const float lx = xc - (float)xx0;
                    acc += vy * vx *
                        ((1.0f - ly) * ((1.0f - lx) * fc[yy0 * W + xx0] + lx * fc[yy0 * W + xx1])
                       +         ly  * ((1.0f - lx) * fc[yy1 * W + xx0] + lx * fc[yy1 * W + xx1]));
                }
            }
            ob[idx] = acc * 0.25f;
        }
    }
}

extern "C" void kernel_launch(void* const* d_in, const int* in_sizes, int n_in,
                              void* d_out, int out_size, void* d_ws, size_t ws_size,
                              hipStream_t stream) {
    const float* f0    = (const float*)d_in[0];
    const float* f1    = (const float*)d_in[1];
    const float* f2    = (const float*)d_in[2];
    const float* f3    = (const float*)d_in[3];
    const float* boxes = (const float*)d_in[4];
    float*       outp  = (float*)d_out;

    const int R = out_size / (CCH * NBIN);   // 512
    roi_direct<<<dim3(R, NCHK), 256, 0, stream>>>(f0, f1, f2, f3, boxes, outp);
}

// Round 4
// 259.969 us; speedup vs baseline: 1.2471x; 1.2471x over previous
//
#include <hip/hip_runtime.h>

// ROIPooler (FPN multi-level ROIAlign, aligned=true), float32 in/out.
// R9: barrier-free wave-private staging + compute.
//  - R8 regression root cause: CAPU=76 was mis-derived; real max window is
//    ~260 16B-units (sz*scale in [14,28) by level assignment), so most ROIs
//    hit the scattered-gather fallback. CAPU=300 restores all-fast-path.
//  - Each wave owns ONE channel: issue <=5 global_load_lds (16B/lane) ->
//    compute per-lane bin params in registers (overlaps DMA flight) ->
//    s_waitcnt vmcnt(0) + sched_barrier (per-wave fence, rule #18) ->
//    16 LDS reads/bin -> store 49 floats. NO __syncthreads anywhere.
//  - LDS 19.2KB, 4 waves/block -> 8 blocks/CU = 32 waves (100% potential).
//  - Grid 512 x 64 = 32768 small blocks (R7's balance; R8's 8192 hurt).

#define OUTD 7
#define CCH  256
#define NBOX 256
#define NC   4               // channels per block = waves per block
#define NCHK (CCH / NC)      // 64 chunks
#define CAPU 300             // 16B units per channel slot (analytic max ~260)
#define CAPF (CAPU * 4)      // 1200 floats per slot
#define NBIN (OUTD * OUTD)   // 49

typedef __attribute__((address_space(1))) unsigned int gu32;
typedef __attribute__((address_space(3))) unsigned int lu32;

__device__ __forceinline__ void gl2lds16(const float* g, float* l) {
    // 16B per lane: LDS dst = uniform base + lane*16, global src per-lane.
    __builtin_amdgcn_global_load_lds((gu32*)(unsigned long long)g, (lu32*)l, 16, 0, 0);
}

__global__ __launch_bounds__(256) void roi_direct(
    const float* __restrict__ f0, const float* __restrict__ f1,
    const float* __restrict__ f2, const float* __restrict__ f3,
    const float* __restrict__ boxes, float* __restrict__ out)
{
    const int roi = blockIdx.x;
    const int t   = threadIdx.x;
    const int wv  = t >> 6;              // wave id = channel within chunk
    const int ln  = t & 63;
    const int c   = blockIdx.y * NC + wv;   // this wave's channel
    const int b   = roi >> 8;            // roi / NBOX

    const float bx1 = boxes[roi * 4 + 0];
    const float by1 = boxes[roi * 4 + 1];
    const float bx2 = boxes[roi * 4 + 2];
    const float by2 = boxes[roi * 4 + 3];

    // Level assignment (uniform).
    const float area = (bx2 - bx1) * (by2 - by1);
    const float sz   = sqrtf(area);
    int lvl = (int)floorf(4.0f + log2f(sz * (1.0f / 224.0f) + 1e-8f));
    lvl = min(max(lvl, 2), 5) - 2;

    const int   wsh   = 8 - lvl;          // log2(W), W = H
    const int   H     = 1 << wsh;
    const int   W     = H;
    const float scale = 1.0f / (float)(4 << lvl);
    const float* f = (lvl == 0) ? f0 : (lvl == 1) ? f1 : (lvl == 2) ? f2 : f3;

    const float x1r = bx1 * scale - 0.5f;
    const float y1r = by1 * scale - 0.5f;
    const float bw  = (bx2 - bx1) * scale * (1.0f / OUTD);
    const float bh  = (by2 - by1) * scale * (1.0f / OUTD);
    const float Wm1 = (float)(W - 1);

    // Window bounds from first/last samples (monotone: bw,bh >= 0).
    const int xf = (int)fminf(fmaxf(x1r + 0.25f * bw, 0.0f), Wm1);
    const int yf = (int)fminf(fmaxf(y1r + 0.25f * bh, 0.0f), Wm1);
    const int xl = min((int)fminf(fmaxf(x1r + 6.75f * bw, 0.0f), Wm1) + 1, W - 1);
    const int yl = min((int)fminf(fmaxf(y1r + 6.75f * bh, 0.0f), Wm1) + 1, W - 1);
    const int x_lo = xf & ~3;            // 16B-align left edge (W pow2 -> rows aligned)
    const int y_lo = yf;
    const int W4 = (xl - x_lo + 4) >> 2; // padded row width, 16B units
    const int Hw = yl - y_lo + 1;
    const int L4 = Hw * W4;              // window size, 16B units
    const int rs = W4 << 2;              // LDS row stride, floats

    __shared__ __align__(16) float s_win[NC * CAPF];   // 19200 B

    const bool fast = (L4 <= CAPU);

    // ---- stage this wave's channel window (fire-and-forget DMA) ----
    const unsigned int cbase = ((unsigned int)(b * CCH + c)) << (2 * wsh);
    if (fast) {
        const unsigned int wbase = ((unsigned int)y_lo << wsh) + (unsigned int)x_lo;
        const unsigned int gmax  = (512u << (2 * wsh)) - 4u;   // tensor floats - 4
        const float invW4 = 1.0f / (float)W4;
        float* lb = s_win + wv * CAPF;
        for (int o0 = 0; o0 < L4; o0 += 64) {
            const int u = o0 + ln;
            if (u < L4) {
                int y  = (int)((float)u * invW4);
                int x4 = u - y * W4;
                if (x4 < 0) { x4 += W4; --y; } else if (x4 >= W4) { x4 -= W4; ++y; }
                unsigned int g = cbase + wbase + ((unsigned int)y << wsh) + ((unsigned int)x4 << 2);
                g = min(g, gmax);         // tensor-end clamp (padding units only)
                gl2lds16(f + g, lb + (o0 << 2));
            }
        }
    }

    // ---- per-lane bin parameters, in registers (overlaps DMA flight) ----
    const int l  = min(ln, 48);          // lanes 49..63: dup bin 48, masked store
    const int oy = l / 7;
    const int ox = l - oy * 7;

    // y samples ia=2oy, ib=2oy+1 ; x samples ja=2ox, jb=2ox+1 ; g=(i+0.5)/2
    const float ysA = y1r + ((float)(2 * oy) + 0.5f) * 0.5f * bh;
    const float ysB = y1r + ((float)(2 * oy + 1) + 0.5f) * 0.5f * bh;
    const float xsA = x1r + ((float)(2 * ox) + 0.5f) * 0.5f * bw;
    const float xsB = x1r + ((float)(2 * ox + 1) + 0.5f) * 0.5f * bw;

    const float vyA = ((ysA >= -1.0f) && (ysA <= (float)H)) ? 1.0f : 0.0f;
    const float vyB = ((ysB >= -1.0f) && (ysB <= (float)H)) ? 1.0f : 0.0f;
    const float vxA = ((xsA >= -1.0f) && (xsA <= (float)W)) ? 1.0f : 0.0f;
    const float vxB = ((xsB >= -1.0f) && (xsB <= (float)W)) ? 1.0f : 0.0f;

    const float ycA = fminf(fmaxf(ysA, 0.0f), Wm1);
    const float ycB = fminf(fmaxf(ysB, 0.0f), Wm1);
    const float xcA = fminf(fmaxf(xsA, 0.0f), Wm1);
    const float xcB = fminf(fmaxf(xsB, 0.0f), Wm1);

    const int yA0 = (int)ycA, yB0 = (int)ycB;
    const int xA0 = (int)xcA, xB0 = (int)xcB;
    const int yA1 = min(yA0 + 1, H - 1), yB1 = min(yB0 + 1, H - 1);
    const int xA1 = min(xA0 + 1, W - 1), xB1 = min(xB0 + 1, W - 1);

    const float lyA = ycA - (float)yA0, lyB = ycB - (float)yB0;
    const float lxA = xcA - (float)xA0, lxB = xcB - (float)xB0;

    const float wyAh = vyA * (1.0f - lyA), wyAl = vyA * lyA;
    const float wyBh = vyB * (1.0f - lyB), wyBl = vyB * lyB;
    const float wxAh = vxA * (1.0f - lxA), wxAl = vxA * lxA;
    const float wxBh = vxB * (1.0f - lxB), wxBl = vxB * lxB;

    float acc;
    if (fast) {
        // window-relative offsets
        const int ryA0 = (yA0 - y_lo) * rs, ryA1 = (yA1 - y_lo) * rs;
        const int ryB0 = (yB0 - y_lo) * rs, ryB1 = (yB1 - y_lo) * rs;
        const int rxA0 = xA0 - x_lo, rxA1 = xA1 - x_lo;
        const int rxB0 = xB0 - x_lo, rxB1 = xB1 - x_lo;

        // per-wave fence: all this wave's DMA deposits are visible after this
        asm volatile("s_waitcnt vmcnt(0)" ::: "memory");
        __builtin_amdgcn_sched_barrier(0);

        const float* w = s_win + wv * CAPF;
        acc =
            wyAh * (wxAh * w[ryA0 + rxA0] + wxAl * w[ryA0 + rxA1])
          + wyAl * (wxAh * w[ryA1 + rxA0] + wxAl * w[ryA1 + rxA1])
          + wyAh * (wxBh * w[ryA0 + rxB0] + wxBl * w[ryA0 + rxB1])
          + wyAl * (wxBh * w[ryA1 + rxB0] + wxBl * w[ryA1 + rxB1])
          + wyBh * (wxAh * w[ryB0 + rxA0] + wxAl * w[ryB0 + rxA1])
          + wyBl * (wxAh * w[ryB1 + rxA0] + wxAl * w[ryB1 + rxA1])
          + wyBh * (wxBh * w[ryB0 + rxB0] + wxBl * w[ryB0 + rxB1])
          + wyBl * (wxBh * w[ryB1 + rxB0] + wxBl * w[ryB1 + rxB1]);
    } else {
        // safety fallback: direct global gather (analytically dead)
        const float* fc = f + cbase;
        const int gA0 = yA0 << wsh, gA1 = yA1 << wsh;
        const int gB0 = yB0 << wsh, gB1 = yB1 << wsh;
        acc =
            wyAh * (wxAh * fc[gA0 + xA0] + wxAl * fc[gA0 + xA1])
          + wyAl * (wxAh * fc[gA1 + xA0] + wxAl * fc[gA1 + xA1])
          + wyAh * (wxBh * fc[gA0 + xB0] + wxBl * fc[gA0 + xB1])
          + wyAl * (wxBh * fc[gA1 + xB0] + wxBl * fc[gA1 + xB1])
          + wyBh * (wxAh * fc[gB0 + xA0] + wxAl * fc[gB0 + xA1])
          + wyBl * (wxAh * fc[gB1 + xA0] + wxAl * fc[gB1 + xA1])
          + wyBh * (wxBh * fc[gB0 + xB0] + wxBl * fc[gB0 + xB1])
          + wyBl * (wxBh * fc[gB1 + xB0] + wxBl * fc[gB1 + xB1]);
    }

    if (ln < NBIN) {
        out[(size_t)roi * (CCH * NBIN) + (size_t)c * NBIN + ln] = acc * 0.25f;
    }
}

extern "C" void kernel_launch(void* const* d_in, const int* in_sizes, int n_in,
                              void* d_out, int out_size, void* d_ws, size_t ws_size,
                              hipStream_t stream) {
    const float* f0    = (const float*)d_in[0];
    const float* f1    = (const float*)d_in[1];
    const float* f2    = (const float*)d_in[2];
    const float* f3    = (const float*)d_in[3];
    const float* boxes = (const float*)d_in[4];
    float*       outp  = (float*)d_out;

    const int R = out_size / (CCH * NBIN);   // 512
    roi_direct<<<dim3(R, NCHK), 256, 0, stream>>>(f0, f1, f2, f3, boxes, outp);
}

// Round 5
// 245.307 us; speedup vs baseline: 1.3217x; 1.0598x over previous
//
#include <hip/hip_runtime.h>

// ROIPooler (FPN multi-level ROIAlign, aligned=true), float32 in/out.
// R10: setup-kernel precompute + 2-channel waves.
//  - roi_setup (512x64, ~3us): per-ROI header + packed bilinear tables
//    (window-relative, ry pre-multiplied by row stride; one 16B load per bin
//    pair) + ushort flat->(y,x4) staging offsets. 640KB workspace, L2-hot
//    (reused by 128 waves per ROI).
//  - roi_main: prologue = 6 hdr words + 4x16B table loads + 5x2B offset
//    loads (~20 VALU vs ~200 in R9). Each wave owns 2 channels: 10 DMAs in
//    flight (2x MLP), one vmcnt(0) drain, 32 LDS reads, 2 stores.
//    Wave count halved to 64k. Grid (chunk, roi): same-ROI blocks adjacent.
//  - Safety: L4>CAPU -> direct-gather fallback (analytically dead);
//    ws too small -> launch R9 monolithic kernel unchanged.

#define OUTD 7
#define CCH  256
#define NBOX 256
#define NBIN 49
#define CAPU 300             // 16B units per channel slot (analytic max ~265)
#define CAPF (CAPU * 4)      // 1200 floats per slot

// main kernel config
#define NC   8               // channels per block = 2 per wave
#define NCHK (CCH / NC)      // 32 chunks

// workspace layout per ROI
#define WS_STRIDE 1280
// 0:   uint hdr[6] = {wsh, ubase, W4, L4, rs, gmax}
// 32:  int2   ytab[14]  (ry0*rs, ry1*rs) window-relative
// 144: float2 wy[14]
// 256: int2   xtab[14]  (rx0, rx1) window-relative
// 368: float2 wx[14]
// 480: ushort offs[304] ((y<<(wsh-2))+x4 per 16B unit)

typedef __attribute__((address_space(1))) unsigned int gu32;
typedef __attribute__((address_space(3))) unsigned int lu32;

__device__ __forceinline__ void gl2lds16(const float* g, float* l) {
    // 16B per lane: LDS dst = uniform base + lane*16, global src per-lane.
    __builtin_amdgcn_global_load_lds((gu32*)(unsigned long long)g, (lu32*)l, 16, 0, 0);
}

struct Geo {
    int wsh, W, H; float x1r, y1r, bw, bh, Wm1;
    int x_lo, y_lo, W4, Hw, L4, rs;
};

__device__ __forceinline__ Geo mkgeo(float bx1, float by1, float bx2, float by2) {
    Geo g;
    const float area = (bx2 - bx1) * (by2 - by1);
    const float sz   = sqrtf(area);
    int lvl = (int)floorf(4.0f + log2f(sz * (1.0f / 224.0f) + 1e-8f));
    lvl = min(max(lvl, 2), 5) - 2;
    g.wsh = 8 - lvl; g.W = 1 << g.wsh; g.H = g.W;
    const float scale = 1.0f / (float)(4 << lvl);
    g.x1r = bx1 * scale - 0.5f;
    g.y1r = by1 * scale - 0.5f;
    g.bw  = (bx2 - bx1) * scale * (1.0f / OUTD);
    g.bh  = (by2 - by1) * scale * (1.0f / OUTD);
    g.Wm1 = (float)(g.W - 1);
    const int xf = (int)fminf(fmaxf(g.x1r + 0.25f * g.bw, 0.0f), g.Wm1);
    const int yf = (int)fminf(fmaxf(g.y1r + 0.25f * g.bh, 0.0f), g.Wm1);
    const int xl = min((int)fminf(fmaxf(g.x1r + 6.75f * g.bw, 0.0f), g.Wm1) + 1, g.W - 1);
    const int yl = min((int)fminf(fmaxf(g.y1r + 6.75f * g.bh, 0.0f), g.Wm1) + 1, g.W - 1);
    g.x_lo = xf & ~3;                 // 16B-align left edge (pow2 W keeps rows aligned)
    g.y_lo = yf;
    g.W4 = (xl - g.x_lo + 4) >> 2;
    g.Hw = yl - g.y_lo + 1;
    g.L4 = g.Hw * g.W4;
    g.rs = g.W4 << 2;
    return g;
}

// ---------------- setup kernel ----------------
__global__ __launch_bounds__(64) void roi_setup(const float* __restrict__ boxes,
                                                unsigned char* __restrict__ ws)
{
    const int roi = blockIdx.x;
    const int ln  = threadIdx.x;
    const Geo g = mkgeo(boxes[roi * 4 + 0], boxes[roi * 4 + 1],
                        boxes[roi * 4 + 2], boxes[roi * 4 + 3]);
    const int b = roi >> 8;
    unsigned char* wr = ws + (size_t)roi * WS_STRIDE;

    if (ln == 0) {
        unsigned int* hdr = (unsigned int*)wr;
        hdr[0] = (unsigned int)g.wsh;
        hdr[1] = ((unsigned int)(b * CCH) << (2 * g.wsh))
               + ((unsigned int)g.y_lo << g.wsh) + (unsigned int)g.x_lo;
        hdr[2] = (unsigned int)g.W4;
        hdr[3] = (unsigned int)g.L4;
        hdr[4] = (unsigned int)g.rs;
        hdr[5] = (512u << (2 * g.wsh)) - 4u;    // tensor floats - 4
    }
    if (ln < 14) {
        const float gg = ((float)ln + 0.5f) * 0.5f;
        const float ys = g.y1r + gg * g.bh;
        const float xs = g.x1r + gg * g.bw;
        const float vy = ((ys >= -1.0f) && (ys <= (float)g.H)) ? 1.0f : 0.0f;
        const float vx = ((xs >= -1.0f) && (xs <= (float)g.W)) ? 1.0f : 0.0f;
        const float yc = fminf(fmaxf(ys, 0.0f), g.Wm1);
        const float xc = fminf(fmaxf(xs, 0.0f), g.Wm1);
        const int y0 = (int)yc, x0 = (int)xc;
        const int y1 = min(y0 + 1, g.H - 1), x1 = min(x0 + 1, g.W - 1);
        const float ly = yc - (float)y0, lx = xc - (float)x0;
        ((int2*)  (wr + 32 ))[ln] = make_int2((y0 - g.y_lo) * g.rs, (y1 - g.y_lo) * g.rs);
        ((float2*)(wr + 144))[ln] = make_float2(vy * (1.0f - ly), vy * ly);
        ((int2*)  (wr + 256))[ln] = make_int2(x0 - g.x_lo, x1 - g.x_lo);
        ((float2*)(wr + 368))[ln] = make_float2(vx * (1.0f - lx), vx * lx);
    }
    unsigned short* offs = (unsigned short*)(wr + 480);
    const int nU = min(g.L4, 304);
    const float invW4 = 1.0f / (float)g.W4;
    for (int u = ln; u < nU; u += 64) {
        int y  = (int)((float)u * invW4);
        int x4 = u - y * g.W4;
        if (x4 < 0) { x4 += g.W4; --y; } else if (x4 >= g.W4) { x4 -= g.W4; ++y; }
        offs[u] = (unsigned short)((y << (g.wsh - 2)) + x4);
    }
}

// ---------------- main kernel ----------------
__global__ __launch_bounds__(256) void roi_main(
    const float* __restrict__ f0, const float* __restrict__ f1,
    const float* __restrict__ f2, const float* __restrict__ f3,
    const float* __restrict__ boxes,
    const unsigned char* __restrict__ ws, float* __restrict__ out)
{
    const int roi = blockIdx.y;
    const int c0  = blockIdx.x * NC;
    const int t   = threadIdx.x;
    const int wv  = t >> 6;
    const int ln  = t & 63;

    const unsigned char* wr  = ws + (size_t)roi * WS_STRIDE;
    const unsigned int*  hdr = (const unsigned int*)wr;
    const unsigned int wsh = hdr[0], ubase = hdr[1];
    const unsigned int L4  = hdr[3], gmax  = hdr[5];

    const int lvl = 8 - (int)wsh;
    const float* f = (lvl == 0) ? f0 : (lvl == 1) ? f1 : (lvl == 2) ? f2 : f3;

    const int l  = min(ln, 48);          // lanes 49..63: dup bin 48, masked store
    const int oy = l / 7;
    const int ox = l - oy * 7;

    // packed per-bin tables: one 16B load per axis-pair
    const int4   ypk = *(const int4*)  (wr + 32  + 16 * oy);  // ryA0,ryA1,ryB0,ryB1
    const float4 wyp = *(const float4*)(wr + 144 + 16 * oy);  // wyAh,wyAl,wyBh,wyBl
    const int4   xpk = *(const int4*)  (wr + 256 + 16 * ox);  // rxA0,rxA1,rxB0,rxB1
    const float4 wxp = *(const float4*)(wr + 368 + 16 * ox);  // wxAh,wxAl,wxBh,wxBl

    const int ca = c0 + wv;
    const int cb = c0 + wv + 4;
    const size_t obase = (size_t)roi * (CCH * NBIN);

    __shared__ __align__(16) float s_win[NC * CAPF];   // 38400 B

    if (L4 <= CAPU) {
        // -------- fast path --------
        const unsigned short* offs = (const unsigned short*)(wr + 480);
        unsigned int rel[5];
        #pragma unroll
        for (int k = 0; k < 5; ++k)
            rel[k] = ((unsigned int)offs[min(ln + (k << 6), (int)L4 - 1)]) << 2;

        float* sa = s_win + wv * CAPF;
        float* sb = s_win + (wv + 4) * CAPF;
        const unsigned int cba = ubase + ((unsigned int)ca << (2 * wsh));
        const unsigned int cbb = ubase + ((unsigned int)cb << (2 * wsh));
        #pragma unroll
        for (int k = 0; k < 5; ++k)
            if (ln + (k << 6) < (int)L4)
                gl2lds16(f + min(cba + rel[k], gmax), sa + (k << 8));
        #pragma unroll
        for (int k = 0; k < 5; ++k)
            if (ln + (k << 6) < (int)L4)
                gl2lds16(f + min(cbb + rel[k], gmax), sb + (k << 8));

        // per-wave DMA drain (no register dest -> manual wait; rule #18 fence)
        asm volatile("s_waitcnt vmcnt(0)" ::: "memory");
        __builtin_amdgcn_sched_barrier(0);

        const float accA =
            wyp.x * (wxp.x * sa[ypk.x + xpk.x] + wxp.y * sa[ypk.x + xpk.y])
          + wyp.y * (wxp.x * sa[ypk.y + xpk.x] + wxp.y * sa[ypk.y + xpk.y])
          + wyp.x * (wxp.z * sa[ypk.x + xpk.z] + wxp.w * sa[ypk.x + xpk.w])
          + wyp.y * (wxp.z * sa[ypk.y + xpk.z] + wxp.w * sa[ypk.y + xpk.w])
          + wyp.z * (wxp.x * sa[ypk.z + xpk.x] + wxp.y * sa[ypk.z + xpk.y])
          + wyp.w * (wxp.x * sa[ypk.w + xpk.x] + wxp.y * sa[ypk.w + xpk.y])
          + wyp.z * (wxp.z * sa[ypk.z + xpk.z] + wxp.w * sa[ypk.z + xpk.w])
          + wyp.w * (wxp.z * sa[ypk.w + xpk.z] + wxp.w * sa[ypk.w + xpk.w]);
        const float accB =
            wyp.x * (wxp.x * sb[ypk.x + xpk.x] + wxp.y * sb[ypk.x + xpk.y])
          + wyp.y * (wxp.x * sb[ypk.y + xpk.x] + wxp.y * sb[ypk.y + xpk.y])
          + wyp.x * (wxp.z * sb[ypk.x + xpk.z] + wxp.w * sb[ypk.x + xpk.w])
          + wyp.y * (wxp.z * sb[ypk.y + xpk.z] + wxp.w * sb[ypk.y + xpk.w])
          + wyp.z * (wxp.x * sb[ypk.z + xpk.x] + wxp.y * sb[ypk.z + xpk.y])
          + wyp.w * (wxp.x * sb[ypk.w + xpk.x] + wxp.y * sb[ypk.w + xpk.y])
          + wyp.z * (wxp.z * sb[ypk.z + xpk.z] + wxp.w * sb[ypk.z + xpk.w])
          + wyp.w * (wxp.z * sb[ypk.w + xpk.z] + wxp.w * sb[ypk.w + xpk.w]);

        if (ln < NBIN) {
            out[obase + (size_t)ca * NBIN + ln] = accA * 0.25f;
            out[obase + (size_t)cb * NBIN + ln] = accB * 0.25f;
        }
    } else {
        // -------- safety fallback: direct global gather (analytically dead) --
        const Geo g = mkgeo(boxes[roi * 4 + 0], boxes[roi * 4 + 1],
                            boxes[roi * 4 + 2], boxes[roi * 4 + 3]);
        const float ysA = g.y1r + ((float)(2 * oy) + 0.5f) * 0.5f * g.bh;
        const float ysB = g.y1r + ((float)(2 * oy + 1) + 0.5f) * 0.5f * g.bh;
        const float xsA = g.x1r + ((float)(2 * ox) + 0.5f) * 0.5f * g.bw;
        const float xsB = g.x1r + ((float)(2 * ox + 1) + 0.5f) * 0.5f * g.bw;
        const float vyA = ((ysA >= -1.0f) && (ysA <= (float)g.H)) ? 1.0f : 0.0f;
        const float vyB = ((ysB >= -1.0f) && (ysB <= (float)g.H)) ? 1.0f : 0.0f;
        const float vxA = ((xsA >= -1.0f) && (xsA <= (float)g.W)) ? 1.0f : 0.0f;
        const float vxB = ((xsB >= -1.0f) && (xsB <= (float)g.W)) ? 1.0f : 0.0f;
        const float ycA = fminf(fmaxf(ysA, 0.0f), g.Wm1);
        const float ycB = fminf(fmaxf(ysB, 0.0f), g.Wm1);
        const float xcA = fminf(fmaxf(xsA, 0.0f), g.Wm1);
        const float xcB = fminf(fmaxf(xsB, 0.0f), g.Wm1);
        const int yA0 = (int)ycA, yB0 = (int)ycB, xA0 = (int)xcA, xB0 = (int)xcB;
        const int yA1 = min(yA0 + 1, g.H - 1), yB1 = min(yB0 + 1, g.H - 1);
        const int xA1 = min(xA0 + 1, g.W - 1), xB1 = min(xB0 + 1, g.W - 1);
        const float lyA = ycA - (float)yA0, lyB = ycB - (float)yB0;
        const float lxA = xcA - (float)xA0, lxB = xcB - (float)xB0;
        const float wyAh = vyA * (1.0f - lyA), wyAl = vyA * lyA;
        const float wyBh = vyB * (1.0f - lyB), wyBl = vyB * lyB;
        const float wxAh = vxA * (1.0f - lxA), wxAl = vxA * lxA;
        const float wxBh = vxB * (1.0f - lxB), wxBl = vxB * lxB;
        const int gA0 = yA0 << g.wsh, gA1 = yA1 << g.wsh;
        const int gB0 = yB0 << g.wsh, gB1 = yB1 << g.wsh;
        const int b = roi >> 8;
        #pragma unroll
        for (int s = 0; s < 2; ++s) {
            const int c = s ? cb : ca;
            const float* fc = f + (((size_t)(b * CCH + c)) << (2 * g.wsh));
            const float acc =
                wyAh * (wxAh * fc[gA0 + xA0] + wxAl * fc[gA0 + xA1])
              + wyAl * (wxAh * fc[gA1 + xA0] + wxAl * fc[gA1 + xA1])
              + wyAh * (wxBh * fc[gA0 + xB0] + wxBl * fc[gA0 + xB1])
              + wyAl * (wxBh * fc[gA1 + xB0] + wxBl * fc[gA1 + xB1])
              + wyBh * (wxAh * fc[gB0 + xA0] + wxAl * fc[gB0 + xA1])
              + wyBl * (wxAh * fc[gB1 + xA0] + wxAl * fc[gB1 + xA1])
              + wyBh * (wxBh * fc[gB0 + xB0] + wxBl * fc[gB0 + xB1])
              + wyBl * (wxBh * fc[gB1 + xB0] + wxBl * fc[gB1 + xB1]);
            if (ln < NBIN)
                out[obase + (size_t)c * NBIN + ln] = acc * 0.25f;
        }
    }
}

// ---------------- monolithic fallback (R9, proven) ----------------
#define MNC 4
__global__ __launch_bounds__(256) void roi_mono(
    const float* __restrict__ f0, const float* __restrict__ f1,
    const float* __restrict__ f2, const float* __restrict__ f3,
    const float* __restrict__ boxes, float* __restrict__ out)
{
    const int roi = blockIdx.x;
    const int t   = threadIdx.x;
    const int wv  = t >> 6;
    const int ln  = t & 63;
    const int c   = blockIdx.y * MNC + wv;
    const int b   = roi >> 8;

    const Geo g = mkgeo(boxes[roi * 4 + 0], boxes[roi * 4 + 1],
                        boxes[roi * 4 + 2], boxes[roi * 4 + 3]);
    const int lvl = 8 - g.wsh;
    const float* f = (lvl == 0) ? f0 : (lvl == 1) ? f1 : (lvl == 2) ? f2 : f3;

    __shared__ __align__(16) float s_win[MNC * CAPF];
    const bool fast = (g.L4 <= CAPU);
    const unsigned int cbase = ((unsigned int)(b * CCH + c)) << (2 * g.wsh);

    if (fast) {
        const unsigned int wbase = ((unsigned int)g.y_lo << g.wsh) + (unsigned int)g.x_lo;
        const unsigned int gmax  = (512u << (2 * g.wsh)) - 4u;
        const float invW4 = 1.0f / (float)g.W4;
        float* lb = s_win + wv * CAPF;
        for (int o0 = 0; o0 < g.L4; o0 += 64) {
            const int u = o0 + ln;
            if (u < g.L4) {
                int y  = (int)((float)u * invW4);
                int x4 = u - y * g.W4;
                if (x4 < 0) { x4 += g.W4; --y; } else if (x4 >= g.W4) { x4 -= g.W4; ++y; }
                unsigned int gg = cbase + wbase + ((unsigned int)y << g.wsh) + ((unsigned int)x4 << 2);
                gl2lds16(f + min(gg, gmax), lb + (o0 << 2));
            }
        }
    }

    const int l  = min(ln, 48);
    const int oy = l / 7;
    const int ox = l - oy * 7;
    const float ysA = g.y1r + ((float)(2 * oy) + 0.5f) * 0.5f * g.bh;
    const float ysB = g.y1r + ((float)(2 * oy + 1) + 0.5f) * 0.5f * g.bh;
    const float xsA = g.x1r + ((float)(2 * ox) + 0.5f) * 0.5f * g.bw;
    const float xsB = g.x1r + ((float)(2 * ox + 1) + 0.5f) * 0.5f * g.bw;
    const float vyA = ((ysA >= -1.0f) && (ysA <= (float)g.H)) ? 1.0f : 0.0f;
    const float vyB = ((ysB >= -1.0f) && (ysB <= (float)g.H)) ? 1.0f : 0.0f;
    const float vxA = ((xsA >= -1.0f) && (xsA <= (float)g.W)) ? 1.0f : 0.0f;
    const float vxB = ((xsB >= -1.0f) && (xsB <= (float)g.W)) ? 1.0f : 0.0f;
    const float ycA = fminf(fmaxf(ysA, 0.0f), g.Wm1);
    const float ycB = fminf(fmaxf(ysB, 0.0f), g.Wm1);
    const float xcA = fminf(fmaxf(xsA, 0.0f), g.Wm1);
    const float xcB = fminf(fmaxf(xsB, 0.0f), g.Wm1);
    const int yA0 = (int)ycA, yB0 = (int)ycB, xA0 = (int)xcA, xB0 = (int)xcB;
    const int yA1 = min(yA0 + 1, g.H - 1), yB1 = min(yB0 + 1, g.H - 1);
    const int xA1 = min(xA0 + 1, g.W - 1), xB1 = min(xB0 + 1, g.W - 1);
    const float lyA = ycA - (float)yA0, lyB = ycB - (float)yB0;
    const float lxA = xcA - (float)xA0, lxB = xcB - (float)xB0;
    const float wyAh = vyA * (1.0f - lyA), wyAl = vyA * lyA;
    const float wyBh = vyB * (1.0f - lyB), wyBl = vyB * lyB;
    const float wxAh = vxA * (1.0f - lxA), wxAl = vxA * lxA;
    const float wxBh = vxB * (1.0f - lxB), wxBl = vxB * lxB;

    float acc;
    if (fast) {
        const int ryA0 = (yA0 - g.y_lo) * g.rs, ryA1 = (yA1 - g.y_lo) * g.rs;
        const int ryB0 = (yB0 - g.y_lo) * g.rs, ryB1 = (yB1 - g.y_lo) * g.rs;
        const int rxA0 = xA0 - g.x_lo, rxA1 = xA1 - g.x_lo;
        const int rxB0 = xB0 - g.x_lo, rxB1 = xB1 - g.x_lo;
        asm volatile("s_waitcnt vmcnt(0)" ::: "memory");
        __builtin_amdgcn_sched_barrier(0);
        const float* w = s_win + wv * CAPF;
        acc =
            wyAh * (wxAh * w[ryA0 + rxA0] + wxAl * w[ryA0 + rxA1])
          + wyAl * (wxAh * w[ryA1 + rxA0] + wxAl * w[ryA1 + rxA1])
          + wyAh * (wxBh * w[ryA0 + rxB0] + wxBl * w[ryA0 + rxB1])
          + wyAl * (wxBh * w[ryA1 + rxB0] + wxBl * w[ryA1 + rxB1])
          + wyBh * (wxAh * w[ryB0 + rxA0] + wxAl * w[ryB0 + rxA1])
          + wyBl * (wxAh * w[ryB1 + rxA0] + wxAl * w[ryB1 + rxA1])
          + wyBh * (wxBh * w[ryB0 + rxB0] + wxBl * w[ryB0 + rxB1])
          + wyBl * (wxBh * w[ryB1 + rxB0] + wxBl * w[ryB1 + rxB1]);
    } else {
        const float* fc = f + cbase;
        const int gA0 = yA0 << g.wsh, gA1 = yA1 << g.wsh;
        const int gB0 = yB0 << g.wsh, gB1 = yB1 << g.wsh;
        acc =
            wyAh * (wxAh * fc[gA0 + xA0] + wxAl * fc[gA0 + xA1])
          + wyAl * (wxAh * fc[gA1 + xA0] + wxAl * fc[gA1 + xA1])
          + wyAh * (wxBh * fc[gA0 + xB0] + wxBl * fc[gA0 + xB1])
          + wyAl * (wxBh * fc[gA1 + xB0] + wxBl * fc[gA1 + xB1])
          + wyBh * (wxAh * fc[gB0 + xA0] + wxAl * fc[gB0 + xA1])
          + wyBl * (wxAh * fc[gB1 + xA0] + wxAl * fc[gB1 + xA1])
          + wyBh * (wxBh * fc[gB0 + xB0] + wxBl * fc[gB0 + xB1])
          + wyBl * (wxBh * fc[gB1 + xB0] + wxBl * fc[gB1 + xB1]);
    }

    if (ln < NBIN) {
        out[(size_t)roi * (CCH * NBIN) + (size_t)c * NBIN + ln] = acc * 0.25f;
    }
}

extern "C" void kernel_launch(void* const* d_in, const int* in_sizes, int n_in,
                              void* d_out, int out_size, void* d_ws, size_t ws_size,
                              hipStream_t stream) {
    const float* f0    = (const float*)d_in[0];
    const float* f1    = (const float*)d_in[1];
    const float* f2    = (const float*)d_in[2];
    const float* f3    = (const float*)d_in[3];
    const float* boxes = (const float*)d_in[4];
    float*       outp  = (float*)d_out;

    const int R = out_size / (CCH * NBIN * 4);   // 512 ROIs (out_size in bytes? no: elems)
    const int Rr = out_size / (CCH * NBIN);      // if out_size is element count
    // out_size semantics match prior rounds: element count -> Rr == 512.
    const int nroi = (Rr == 512 || Rr == 2 * NBOX) ? Rr : (R > 0 ? R : Rr);

    if (ws_size >= (size_t)nroi * WS_STRIDE) {
        roi_setup<<<nroi, 64, 0, stream>>>(boxes, (unsigned char*)d_ws);
        roi_main<<<dim3(NCHK, nroi), 256, 0, stream>>>(
            f0, f1, f2, f3, boxes, (const unsigned char*)d_ws, outp);
    } else {
        roi_mono<<<dim3(nroi, CCH / MNC), 256, 0, stream>>>(f0, f1, f2, f3, boxes, outp);
    }
}